// Round 1
// 777.543 us; speedup vs baseline: 1.0074x; 1.0074x over previous
//
#include <hip/hip_runtime.h>

typedef unsigned short u16;
typedef unsigned int   u32;

#define D_MODEL 1024
#define D_INNER 2048
#define D_STATE 16
#define SEQLEN  2048
#define BATCH   4
#define NROWS   (BATCH*SEQLEN)   // 8192
#define CHUNK   128
#define NCHUNK  (SEQLEN/CHUNK)   // 16

__device__ __forceinline__ float b2f(u16 v){
  union { u32 i; float f; } u; u.i = ((u32)v) << 16; return u.f;
}
__device__ __forceinline__ u16 f2b(float f){
  union { float f; u32 i; } u; u.f = f;
  u32 x = u.i;
  return (u16)((x + 0x7fffu + ((x >> 16) & 1u)) >> 16);  // RNE
}
__device__ __forceinline__ float h2f(u16 v){
  _Float16 h; __builtin_memcpy(&h, &v, 2); return (float)h;
}
__device__ __forceinline__ u16 f2h(float f){
  _Float16 h = (_Float16)f; u16 v; __builtin_memcpy(&v, &h, 2); return v;
}

typedef __bf16 bf16x8 __attribute__((ext_vector_type(8)));
typedef float  f32x4  __attribute__((ext_vector_type(4)));

// async global->LDS, 16B per lane; data for lane i lands at lds + i*16B.
__device__ __forceinline__ void async16(u16* lds, const u16* g){
  __builtin_amdgcn_global_load_lds(
      (const __attribute__((address_space(1))) void*)g,
      (__attribute__((address_space(3))) void*)lds,
      16, 0, 0);
}

// ---------------------------------------------------------------------------
// fp32 [Kd][Nd] -> bf16 transposed [Nd][Kd]   (32x32 LDS tiles)
// ---------------------------------------------------------------------------
__global__ __launch_bounds__(256) void wcvt_t_kernel(
    const float* __restrict__ W, u16* __restrict__ Bt, int Kd, int Nd)
{
  __shared__ u16 tile[32][33];
  const int n0 = blockIdx.x*32, k0 = blockIdx.y*32;
  const int tx = threadIdx.x & 31, ty = threadIdx.x >> 5;  // ty 0..7
  #pragma unroll
  for (int i=0;i<32;i+=8)
    tile[ty+i][tx] = f2b(W[(size_t)(k0+ty+i)*Nd + n0+tx]);   // tile[k][n]
  __syncthreads();
  #pragma unroll
  for (int i=0;i<32;i+=8)
    Bt[(size_t)(n0+ty+i)*Kd + k0+tx] = tile[tx][ty+i];
}

// Wx [2048][32] cols 16..31 -> Wxt bf16 [16][2048]
__global__ __launch_bounds__(256) void wxcvt_kernel(
    const float* __restrict__ Wx, u16* __restrict__ Wxt)
{
  const int k = blockIdx.x*256 + threadIdx.x;   // 0..2047
  #pragma unroll
  for (int n=0;n<16;n++)
    Wxt[n*D_INNER + k] = f2b(Wx[(size_t)k*32 + 16 + n]);
}

// ---------------------------------------------------------------------------
// Fused LayerNorm: x[row][1024] fp32 -> xn bf16
// ---------------------------------------------------------------------------
__global__ __launch_bounds__(256) void ln_kernel(
    const float* __restrict__ x, const float* __restrict__ g,
    const float* __restrict__ be, u16* __restrict__ xn)
{
  const int row = blockIdx.x;
  const float* xr = x + (size_t)row * D_MODEL;
  const int tid = threadIdx.x;
  float v[4]; float s = 0.f, s2 = 0.f;
  #pragma unroll
  for (int j=0;j<4;j++){
    float f = xr[tid + 256*j];
    v[j] = f; s += f; s2 += f*f;
  }
  #pragma unroll
  for (int o=32;o>0;o>>=1){ s += __shfl_down(s,o); s2 += __shfl_down(s2,o); }
  __shared__ float sh[8];
  const int wave = tid>>6, lane = tid&63;
  if (lane==0){ sh[wave]=s; sh[4+wave]=s2; }
  __syncthreads();
  const float ts  = sh[0]+sh[1]+sh[2]+sh[3];
  const float ts2 = sh[4]+sh[5]+sh[6]+sh[7];
  const float mu  = ts * (1.f/D_MODEL);
  const float var = ts2 * (1.f/D_MODEL) - mu*mu;
  const float rstd = rsqrtf(var + 1e-5f);
  u16* xo = xn + (size_t)row * D_MODEL;
  #pragma unroll
  for (int j=0;j<4;j++){
    int i = tid + 256*j;
    xo[i] = f2b((v[j]-mu)*rstd * g[i] + be[i]);
  }
}

// ---------------------------------------------------------------------------
// 256x256 MFMA GEMM, BK=32, 4-deep LDS ring (128 KB), counted-vmcnt pipeline.
// 8 waves (2M x 4N), 128x64 output per wave. Per K-tile: 2 phases of 16 MFMA
// with raw s_barrier + lgkmcnt(0); staging for K-tile kt+3 issued in phase A,
// single s_waitcnt vmcnt(8) per K-tile (8 loads of kt+2/kt+3 stay in flight
// across the barrier -> T4 counted vmcnt; never drained to 0 in main loop).
// Swizzle: logical k-granule g stored at p = g ^ ((row>>1)&3) (16B granules,
// verified 0-conflict scheme) applied on the pre-swizzled GLOBAL source so
// global_load_lds destinations stay linear.
// A [M][K] bf16 ; Bt [N][K] bf16 (pre-transposed).
// EPI 0: bf16 ; EPI 1: softplus(v+bias)->fp16 ; EPI 2: v+resid->fp32
// ---------------------------------------------------------------------------
template<int EPI>
__global__ __launch_bounds__(512) void gemm256(
    const u16* __restrict__ A, const u16* __restrict__ Bt,
    const float* __restrict__ bias, const float* __restrict__ resid,
    void* __restrict__ outv, int M, int N, int K, int gx, int gy)
{
  __shared__ __align__(16) u16 As[4*8192];   // 4 bufs x 16 KB (256 rows x 32)
  __shared__ __align__(16) u16 Bs[4*8192];
  const int tid  = threadIdx.x;
  const int wave = tid >> 6, lane = tid & 63;
  const int quad = lane >> 4, l16 = lane & 15;
  const int wm = wave >> 2, wn = wave & 3;   // 2 x 4 wave grid

  // XCD-aware swizzle (needs gx % 8 == 0); fallback: walk m fastest.
  const int lid = blockIdx.x;
  int bx, by;
  if ((gx & 7) == 0) {
    const int xcd = lid & 7, q = lid >> 3;
    const int cpx = gx >> 3;
    const int qd  = q / gy;
    bx = xcd*cpx + qd;
    by = q - qd*gy;
  } else {
    bx = lid / gy;
    by = lid - bx*gy;
  }
  const int m0 = by*256, n0 = bx*256;

  // ---- staging addresses (pre-swizzled global source, linear LDS dest) ----
  const int gl   = (tid & 3) ^ ((tid >> 3) & 3);   // logical granule for phys p=tid&3
  const int srow = tid >> 2;                       // 0..127
  const u16* sA0 = A  + (size_t)(m0 + srow)*K       + gl*8;
  const u16* sA1 = A  + (size_t)(m0 + 128 + srow)*K + gl*8;
  const u16* sB0 = Bt + (size_t)(n0 + srow)*K       + gl*8;
  const u16* sB1 = Bt + (size_t)(n0 + 128 + srow)*K + gl*8;
  u16* dA = As + wave*512;   // wave-uniform base; +buf*8192, +4096 for rows 128..255
  u16* dB = Bs + wave*512;

  // ---- fragment read bases (swizzled read side) ----
  const int swz = quad ^ ((l16 >> 1) & 3);
  const char* aBase = (const char*)As + (wm*128 + l16)*64 + swz*16;
  const char* bBase = (const char*)Bs + (wn*64  + l16)*64 + swz*16;

  f32x4 acc[8][4];
  #pragma unroll
  for (int i=0;i<8;i++)
    #pragma unroll
    for (int j=0;j<4;j++) acc[i][j] = (f32x4){0.f,0.f,0.f,0.f};

  const int KT = K >> 5;

  // ---- prologue: stage kt = 0,1,2 (12 loads/wave) ----
  #pragma unroll
  for (int p=0;p<3;p++){
    const int ko = p*32;
    u16* da = dA + p*8192; u16* db = dB + p*8192;
    async16(da,        sA0 + ko);
    async16(da + 4096, sA1 + ko);
    async16(db,        sB0 + ko);
    async16(db + 4096, sB1 + ko);
  }
  asm volatile("s_waitcnt vmcnt(8)" ::: "memory");   // kt=0 landed, 8 in flight
  __builtin_amdgcn_s_barrier();
  __builtin_amdgcn_sched_barrier(0);

  for (int kt = 0; kt < KT; ++kt){
    const int c = kt & 3;
    const char* aT = aBase + c*16384;
    const char* bT = bBase + c*16384;

    // ---- phase A: ds-reads, stage kt+3, 16 MFMA ----
    bf16x8 af[4], bfr[4];
    #pragma unroll
    for (int mf=0;mf<4;mf++) af[mf]  = *(const bf16x8*)(aT + mf*1024);
    #pragma unroll
    for (int nf=0;nf<4;nf++) bfr[nf] = *(const bf16x8*)(bT + nf*1024);
    {
      int k3 = kt + 3; k3 = (k3 < KT) ? k3 : (KT-1);  // clamp keeps vmcnt uniform
      const int b3 = (kt + 3) & 3;                    // dest buf is dead (read at kt-1)
      const int ko = k3*32;
      u16* da = dA + b3*8192; u16* db = dB + b3*8192;
      async16(da,        sA0 + ko);
      async16(da + 4096, sA1 + ko);
      async16(db,        sB0 + ko);
      async16(db + 4096, sB1 + ko);
    }
    __builtin_amdgcn_s_barrier();
    asm volatile("s_waitcnt lgkmcnt(0)" ::: "memory");
    __builtin_amdgcn_sched_barrier(0);
    __builtin_amdgcn_s_setprio(1);
    #pragma unroll
    for (int mf=0;mf<4;mf++)
      #pragma unroll
      for (int nf=0;nf<4;nf++)
        acc[mf][nf] = __builtin_amdgcn_mfma_f32_16x16x32_bf16(af[mf], bfr[nf], acc[mf][nf], 0, 0, 0);
    __builtin_amdgcn_s_setprio(0);
    __builtin_amdgcn_s_barrier();

    // ---- phase B: 4 ds-reads, 16 MFMA, counted vmcnt at tile boundary ----
    bf16x8 ag[4];
    #pragma unroll
    for (int mf=0;mf<4;mf++) ag[mf] = *(const bf16x8*)(aT + (4+mf)*1024);
    __builtin_amdgcn_s_barrier();
    asm volatile("s_waitcnt lgkmcnt(0)" ::: "memory");
    __builtin_amdgcn_sched_barrier(0);
    __builtin_amdgcn_s_setprio(1);
    #pragma unroll
    for (int mf=0;mf<4;mf++)
      #pragma unroll
      for (int nf=0;nf<4;nf++)
        acc[4+mf][nf] = __builtin_amdgcn_mfma_f32_16x16x32_bf16(ag[mf], bfr[nf], acc[4+mf][nf], 0, 0, 0);
    __builtin_amdgcn_s_setprio(0);
    asm volatile("s_waitcnt vmcnt(8)" ::: "memory");  // kt+1 ready; kt+2/kt+3 stay in flight
    __builtin_amdgcn_s_barrier();
    __builtin_amdgcn_sched_barrier(0);
  }

  // ---- epilogue ----
  #pragma unroll
  for (int mf=0; mf<8; mf++){
    #pragma unroll
    for (int nf=0; nf<4; nf++){
      const int col = n0 + wn*64 + nf*16 + l16;
      #pragma unroll
      for (int j=0;j<4;j++){
        const int row = m0 + wm*128 + mf*16 + quad*4 + j;
        float v = acc[mf][nf][j];
        if (EPI == 1) {
          v += bias[col];
          v = (v > 20.f) ? v : log1pf(__expf(v));
          ((u16*)outv)[(size_t)row*N + col] = f2h(v);       // delta fp16
        } else if (EPI == 2) {
          v += resid[(size_t)row*N + col];
          ((float*)outv)[(size_t)row*N + col] = v;          // final out fp32
        } else {
          ((u16*)outv)[(size_t)row*N + col] = f2b(v);       // bf16 activation
        }
      }
    }
  }
}

// ---------------------------------------------------------------------------
// Causal depthwise conv(width 4) + bias + SiLU, 8 channels/thread vectorized.
// ---------------------------------------------------------------------------
__global__ __launch_bounds__(256) void conv_silu_kernel(
    const u16* __restrict__ xz, const float* __restrict__ cw,
    const float* __restrict__ cb, u16* __restrict__ u)
{
  const int idx = blockIdx.x*256 + threadIdx.x;   // (bt, c-group)
  const int c0 = (idx & 255) * 8;
  const int bt = idx >> 8;
  const int t  = bt & (SEQLEN-1);
  float acc[8];
  #pragma unroll
  for (int j=0;j<8;j++) acc[j] = cb[c0+j];
  #pragma unroll
  for (int k=0;k<4;k++){
    if (t - 3 + k >= 0){
      bf16x8 xv = *reinterpret_cast<const bf16x8*>(xz + (size_t)(bt-3+k)*4096 + c0);
      #pragma unroll
      for (int j=0;j<8;j++)
        acc[j] = fmaf(cw[(c0+j)*4 + k], (float)xv[j], acc[j]);
    }
  }
  u16 o[8];
  #pragma unroll
  for (int j=0;j<8;j++){
    float sv = acc[j] / (1.f + __expf(-acc[j]));
    o[j] = f2b(sv);
  }
  __builtin_memcpy(u + (size_t)bt*D_INNER + c0, o, 16);
}

// ---------------------------------------------------------------------------
// x_proj (cols 16..31 only): one wave per row, lane=(kq,n), bf16x8 both streams.
// ---------------------------------------------------------------------------
__global__ __launch_bounds__(256) void xproj_kernel(
    const u16* __restrict__ u, const u16* __restrict__ Wxt, float* __restrict__ Bm)
{
  const int wave = threadIdx.x >> 6, lane = threadIdx.x & 63;
  const int m = blockIdx.x*4 + wave;
  const int n = lane & 15, kq = lane >> 4;
  const u16* ur = u   + (size_t)m*D_INNER + kq*512;
  const u16* wr = Wxt + (size_t)n*D_INNER + kq*512;
  float acc = 0.f;
  #pragma unroll 4
  for (int i=0;i<512;i+=8){
    bf16x8 uv = *reinterpret_cast<const bf16x8*>(ur + i);
    bf16x8 wv = *reinterpret_cast<const bf16x8*>(wr + i);
    #pragma unroll
    for (int j=0;j<8;j++) acc = fmaf((float)uv[j], (float)wv[j], acc);
  }
  acc += __shfl_xor(acc, 16);
  acc += __shfl_xor(acc, 32);
  if (lane < 16) Bm[(size_t)m*16 + n] = acc;
}

// ---------------------------------------------------------------------------
// Chunked selective scan, 3 passes (exact linear-recurrence decomposition).
// ---------------------------------------------------------------------------
__global__ __launch_bounds__(256) void scan_partial(
    const u16* __restrict__ uu, const u16* __restrict__ delta16,
    const float* __restrict__ Bm, const float* __restrict__ Alog,
    float* __restrict__ hend, float* __restrict__ sumdt)
{
  const int b = blockIdx.y, ch = blockIdx.z;
  const int c = blockIdx.x*256 + threadIdx.x;
  const int row0 = b*SEQLEN + ch*CHUNK;
  float A[16], h[16];
  #pragma unroll
  for (int s=0;s<16;s++){ A[s] = -__expf(Alog[c*16+s]); h[s]=0.f; }
  __shared__ float Bsh[CHUNK*16];
  const float* src = Bm + (size_t)row0*16;
  #pragma unroll
  for (int j=0;j<8;j++) Bsh[threadIdx.x + 256*j] = src[threadIdx.x + 256*j];
  __syncthreads();

  float S = 0.f;
  float dta[8], uva[8], dtb[8], uvb[8];
  #pragma unroll
  for (int j=0;j<8;j++){
    size_t r = (size_t)(row0+j);
    dta[j] = h2f(delta16[r*D_INNER+c]);
    uva[j] = b2f(uu[r*D_INNER+c]);
  }
  #pragma unroll 1
  for (int g=0; g<CHUNK; g+=16){
    #pragma unroll
    for (int j=0;j<8;j++){
      int tl = g+8+j; tl = tl < CHUNK ? tl : CHUNK-1;
      size_t r = (size_t)(row0+tl);
      dtb[j] = h2f(delta16[r*D_INNER+c]);
      uvb[j] = b2f(uu[r*D_INNER+c]);
    }
    #pragma unroll
    for (int j=0;j<8;j++){
      float dt=dta[j], uv=uva[j]; S += dt; float xv=dt*uv;
      const float* Bt = &Bsh[(g+j)*16];
      #pragma unroll
      for (int s=0;s<16;s++) h[s] = fmaf(h[s], __expf(dt*A[s]), xv*Bt[s]);
    }
    #pragma unroll
    for (int j=0;j<8;j++){
      int tl = g+16+j; tl = tl < CHUNK ? tl : CHUNK-1;
      size_t r = (size_t)(row0+tl);
      dta[j] = h2f(delta16[r*D_INNER+c]);
      uva[j] = b2f(uu[r*D_INNER+c]);
    }
    #pragma unroll
    for (int j=0;j<8;j++){
      float dt=dtb[j], uv=uvb[j]; S += dt; float xv=dt*uv;
      const float* Bt = &Bsh[(g+8+j)*16];
      #pragma unroll
      for (int s=0;s<16;s++) h[s] = fmaf(h[s], __expf(dt*A[s]), xv*Bt[s]);
    }
  }
  const size_t base = ((size_t)(b*NCHUNK+ch)*16)*D_INNER + c;
  #pragma unroll
  for (int s=0;s<16;s++) hend[base + (size_t)s*D_INNER] = h[s];
  sumdt[(size_t)(b*NCHUNK+ch)*D_INNER + c] = S;
}

__global__ __launch_bounds__(256) void scan_combine(
    const float* __restrict__ hend, const float* __restrict__ sumdt,
    const float* __restrict__ Alog, float* __restrict__ hin)
{
  const int b = blockIdx.y;
  const int c = blockIdx.x*256 + threadIdx.x;
  float A[16], h[16];
  #pragma unroll
  for (int s=0;s<16;s++){ A[s] = -__expf(Alog[c*16+s]); h[s]=0.f; }
  #pragma unroll 1
  for (int k=0;k<NCHUNK;k++){
    const size_t base = ((size_t)(b*NCHUNK+k)*16)*D_INNER + c;
    #pragma unroll
    for (int s=0;s<16;s++) hin[base + (size_t)s*D_INNER] = h[s];
    const float S = sumdt[(size_t)(b*NCHUNK+k)*D_INNER + c];
    #pragma unroll
    for (int s=0;s<16;s++)
      h[s] = fmaf(h[s], __expf(S*A[s]), hend[base + (size_t)s*D_INNER]);
  }
}

__global__ __launch_bounds__(256) void scan_final(
    const u16* __restrict__ uu, const u16* __restrict__ delta16,
    const float* __restrict__ Bm, const u16* __restrict__ xz,
    const float* __restrict__ Alog, const float* __restrict__ Dpar,
    const float* __restrict__ hin, u16* __restrict__ yg)
{
  const int b = blockIdx.y, ch = blockIdx.z;
  const int c = blockIdx.x*256 + threadIdx.x;
  const int row0 = b*SEQLEN + ch*CHUNK;
  float A[16], h[16];
  const size_t base = ((size_t)(b*NCHUNK+ch)*16)*D_INNER + c;
  #pragma unroll
  for (int s=0;s<16;s++){
    A[s] = -__expf(Alog[c*16+s]);
    h[s] = hin[base + (size_t)s*D_INNER];
  }
  const float Dc = Dpar[c];
  __shared__ float Bsh[CHUNK*16];
  const float* src = Bm + (size_t)row0*16;
  #pragma unroll
  for (int j=0;j<8;j++) Bsh[threadIdx.x + 256*j] = src[threadIdx.x + 256*j];
  __syncthreads();

  float dta[8], uva[8], zva[8], dtb[8], uvb[8], zvb[8];
  #pragma unroll
  for (int j=0;j<8;j++){
    size_t r = (size_t)(row0+j);
    dta[j] = h2f(delta16[r*D_INNER+c]);
    uva[j] = b2f(uu[r*D_INNER+c]);
    zva[j] = b2f(xz[r*4096 + D_INNER + c]);
  }
  #pragma unroll 1
  for (int g=0; g<CHUNK; g+=16){
    #pragma unroll
    for (int j=0;j<8;j++){
      int tl = g+8+j; tl = tl < CHUNK ? tl : CHUNK-1;
      size_t r = (size_t)(row0+tl);
      dtb[j] = h2f(delta16[r*D_INNER+c]);
      uvb[j] = b2f(uu[r*D_INNER+c]);
      zvb[j] = b2f(xz[r*4096 + D_INNER + c]);
    }
    #pragma unroll
    for (int j=0;j<8;j++){
      float dt=dta[j], uv=uva[j], zv=zva[j];
      float xv=dt*uv, y=0.f;
      const float* Bt = &Bsh[(g+j)*16];
      #pragma unroll
      for (int s=0;s<16;s++){
        h[s] = fmaf(h[s], __expf(dt*A[s]), xv*Bt[s]);
        y += h[s];
      }
      y = fmaf(uv, Dc, y);
      float gz = zv/(1.f+__expf(-zv));
      yg[(size_t)(row0+g+j)*D_INNER + c] = f2b(y*gz);
    }
    #pragma unroll
    for (int j=0;j<8;j++){
      int tl = g+16+j; tl = tl < CHUNK ? tl : CHUNK-1;
      size_t r = (size_t)(row0+tl);
      dta[j] = h2f(delta16[r*D_INNER+c]);
      uva[j] = b2f(uu[r*D_INNER+c]);
      zva[j] = b2f(xz[r*4096 + D_INNER + c]);
    }
    #pragma unroll
    for (int j=0;j<8;j++){
      float dt=dtb[j], uv=uvb[j], zv=zvb[j];
      float xv=dt*uv, y=0.f;
      const float* Bt = &Bsh[(g+8+j)*16];
      #pragma unroll
      for (int s=0;s<16;s++){
        h[s] = fmaf(h[s], __expf(dt*A[s]), xv*Bt[s]);
        y += h[s];
      }
      y = fmaf(uv, Dc, y);
      float gz = zv/(1.f+__expf(-zv));
      yg[(size_t)(row0+g+8+j)*D_INNER + c] = f2b(y*gz);
    }
  }
}

// ---------------------------------------------------------------------------
extern "C" void kernel_launch(void* const* d_in, const int* in_sizes, int n_in,
                              void* d_out, int out_size, void* d_ws, size_t ws_size,
                              hipStream_t stream)
{
  const float* x    = (const float*)d_in[0];
  const float* lng  = (const float*)d_in[1];
  const float* lnb  = (const float*)d_in[2];
  const float* W1   = (const float*)d_in[3];
  const float* cw   = (const float*)d_in[4];
  const float* cb   = (const float*)d_in[5];
  const float* Wx   = (const float*)d_in[6];
  const float* Wdt  = (const float*)d_in[7];
  const float* dtb  = (const float*)d_in[8];
  const float* Alog = (const float*)d_in[9];
  const float* Dpar = (const float*)d_in[10];
  const float* Wout = (const float*)d_in[11];

  // workspace layout (MiB offsets), total ~199 MiB
  char* ws = (char*)d_ws;
  u16*   dlt   = (u16*)(ws);
  u16*   xn    = (u16*)(ws);                 // alias (sequenced)
  u16*   xz    = (u16*)(ws + (32llu<<20));
  u16*   uu    = (u16*)(ws + (96llu<<20));
  float* Bm    = (float*)(ws + (128llu<<20));
  u16*   W1t   = (u16*)(ws + (129llu<<20));
  u16*   Wdtt  = (u16*)(ws + (137llu<<20));
  u16*   Woutt = (u16*)(ws + (145llu<<20));
  u16*   yg    = (u16*)(ws + (149llu<<20));
  float* hend  = (float*)(ws + (181llu<<20));
  float* sumdt = (float*)(ws + (189llu<<20));
  float* hin   = (float*)(ws + (190llu<<20));
  u16*   Wxt   = (u16*)(ws + (198llu<<20));

  // weights -> bf16, transposed to [N][K]
  wcvt_t_kernel<<<dim3(2*D_INNER/32, D_MODEL/32), 256, 0, stream>>>(W1,  W1t,  D_MODEL, 2*D_INNER);
  wcvt_t_kernel<<<dim3(D_INNER/32,  D_INNER/32), 256, 0, stream>>>(Wdt, Wdtt, D_INNER, D_INNER);
  wcvt_t_kernel<<<dim3(D_MODEL/32,  D_INNER/32), 256, 0, stream>>>(Wout,Woutt,D_INNER, D_MODEL);
  wxcvt_kernel<<<D_INNER/256, 256, 0, stream>>>(Wx, Wxt);

  ln_kernel<<<NROWS, 256, 0, stream>>>(x, lng, lnb, xn);

  {
    const int gx = 2*D_INNER/256, gy = NROWS/256;   // 16 x 32
    gemm256<0><<<gx*gy, 512, 0, stream>>>(
        xn, W1t, nullptr, nullptr, (void*)xz, NROWS, 2*D_INNER, D_MODEL, gx, gy);
  }

  conv_silu_kernel<<<(NROWS*D_INNER/8)/256, 256, 0, stream>>>(xz, cw, cb, uu);

  xproj_kernel<<<NROWS/4, 256, 0, stream>>>(uu, Wxt, Bm);

  {
    const int gx = D_INNER/256, gy = NROWS/256;     // 8 x 32
    gemm256<1><<<gx*gy, 512, 0, stream>>>(
        uu, Wdtt, dtb, nullptr, (void*)dlt, NROWS, D_INNER, D_INNER, gx, gy);
  }

  scan_partial<<<dim3(D_INNER/256, BATCH, NCHUNK), 256, 0, stream>>>(
      uu, dlt, Bm, Alog, hend, sumdt);
  scan_combine<<<dim3(D_INNER/256, BATCH), 256, 0, stream>>>(
      hend, sumdt, Alog, hin);
  scan_final<<<dim3(D_INNER/256, BATCH, NCHUNK), 256, 0, stream>>>(
      uu, dlt, Bm, xz, Alog, Dpar, hin, yg);

  {
    const int gx = D_MODEL/256, gy = NROWS/256;     // 4 x 32
    gemm256<2><<<gx*gy, 512, 0, stream>>>(
        yg, Woutt, nullptr, x, d_out, NROWS, D_MODEL, D_INNER, gx, gy);
  }

  (void)in_sizes; (void)n_in; (void)out_size; (void)ws_size;
}